// Round 1
// baseline (842.456 us; speedup 1.0000x reference)
//
#include <hip/hip_runtime.h>

#define IMG_H 1024
#define IMG_W 1024
#define NIMG  16
#define MAXD  20

// -------- Kernel 1: binarize + horizontal (per-row) capped 1-D distance ----
// g(x) = 0 if binary(x)==1 else min(MAXD, distance along the row to the
// nearest binary==1 pixel). Note g==0 <=> binary==1 (encodes the mask too).

__device__ inline int scan1d(const unsigned char* __restrict__ b, int x) {
    if (b[x]) return 0;
    #pragma unroll 1
    for (int d = 1; d <= MAXD; ++d) {
        bool hit = false;
        if (x - d >= 0   && b[x - d]) hit = true;
        if (x + d < IMG_W && b[x + d]) hit = true;
        if (hit) return d;
    }
    return MAXD;
}

__global__ __launch_bounds__(256) void hpass_kernel(
    const float* __restrict__ pred, const int* __restrict__ targ,
    unsigned char* __restrict__ gp, unsigned char* __restrict__ gt)
{
    __shared__ unsigned char pb[IMG_W];
    __shared__ unsigned char tb[IMG_W];
    const int row = blockIdx.x;                      // 0 .. NIMG*IMG_H-1
    const long long base = (long long)row * IMG_W;
    const int tid = threadIdx.x;                     // 256 threads, 4 px each

    const float4 p4 = reinterpret_cast<const float4*>(pred + base)[tid];
    const int4  t4  = reinterpret_cast<const int4*>(targ + base)[tid];
    uchar4 pv, tv;
    pv.x = p4.x > 0.0f; pv.y = p4.y > 0.0f; pv.z = p4.z > 0.0f; pv.w = p4.w > 0.0f;
    tv.x = t4.x != 0;   tv.y = t4.y != 0;   tv.z = t4.z != 0;   tv.w = t4.w != 0;
    reinterpret_cast<uchar4*>(pb)[tid] = pv;
    reinterpret_cast<uchar4*>(tb)[tid] = tv;
    __syncthreads();

    uchar4 gpv, gtv;
    unsigned char* gpp = reinterpret_cast<unsigned char*>(&gpv);
    unsigned char* gtp = reinterpret_cast<unsigned char*>(&gtv);
    #pragma unroll
    for (int j = 0; j < 4; ++j) {
        const int x = tid * 4 + j;
        gpp[j] = (unsigned char)scan1d(pb, x);
        gtp[j] = (unsigned char)scan1d(tb, x);
    }
    reinterpret_cast<uchar4*>(gp + base)[tid] = gpv;
    reinterpret_cast<uchar4*>(gt + base)[tid] = gtv;
}

// -------- Kernel 2: vertical pass D(x,y)=min_d max(d, g(x±d, y)) + reduce ---

__device__ inline void vscan(const unsigned char* __restrict__ g, int base, int r,
                             unsigned int c, int res[4])
{
    int b0 = (int)(c & 255u), b1 = (int)((c >> 8) & 255u);
    int b2 = (int)((c >> 16) & 255u), b3 = (int)((c >> 24) & 255u);
    int bmax = max(max(b0, b1), max(b2, b3));
    #pragma unroll 1
    for (int d = 1; d <= MAXD; ++d) {
        if (bmax <= d) break;                 // all future terms >= d
        unsigned int up = 0xFFFFFFFFu, dn = 0xFFFFFFFFu;
        if (r - d >= 0)    up = *reinterpret_cast<const unsigned int*>(g + base - (d << 10));
        if (r + d < IMG_H) dn = *reinterpret_cast<const unsigned int*>(g + base + (d << 10));
        const int m0 = min((int)(up & 255u),         (int)(dn & 255u));
        const int m1 = min((int)((up >> 8) & 255u),  (int)((dn >> 8) & 255u));
        const int m2 = min((int)((up >> 16) & 255u), (int)((dn >> 16) & 255u));
        const int m3 = min((int)((up >> 24) & 255u), (int)((dn >> 24) & 255u));
        b0 = min(b0, max(d, m0));
        b1 = min(b1, max(d, m1));
        b2 = min(b2, max(d, m2));
        b3 = min(b3, max(d, m3));
        bmax = max(max(b0, b1), max(b2, b3));
    }
    res[0] = b0; res[1] = b1; res[2] = b2; res[3] = b3;
}

__global__ __launch_bounds__(256) void vpass_kernel(
    const unsigned char* __restrict__ gp, const unsigned char* __restrict__ gt,
    unsigned int* __restrict__ sums)
{
    const int t = blockIdx.x * 256 + threadIdx.x;
    const int base = t * 4;                          // 4 consecutive pixels
    const int r = (base >> 10) & (IMG_H - 1);        // row within image

    const unsigned int cp = *reinterpret_cast<const unsigned int*>(gp + base);
    const unsigned int ct = *reinterpret_cast<const unsigned int*>(gt + base);

    int Dp[4], Dt[4];
    vscan(gp, base, r, cp, Dp);
    vscan(gt, base, r, ct, Dt);

    unsigned int s1 = 0, s2 = 0, s3 = 0, s4 = 0;
    #pragma unroll
    for (int j = 0; j < 4; ++j) {
        const unsigned int tj = (((ct >> (8 * j)) & 255u) == 0u) ? 1u : 0u; // target==1
        const unsigned int pj = (((cp >> (8 * j)) & 255u) == 0u) ? 1u : 0u; // pred_bin==1
        s1 += tj * (unsigned int)Dp[j];
        s2 += tj;
        s3 += pj * (unsigned int)Dt[j];
        s4 += pj;
    }

    // wave reduce (64 lanes), then LDS combine, 4 atomics per block
    for (int o = 32; o > 0; o >>= 1) {
        s1 += __shfl_down(s1, o);
        s2 += __shfl_down(s2, o);
        s3 += __shfl_down(s3, o);
        s4 += __shfl_down(s4, o);
    }
    __shared__ unsigned int ls[4];
    if (threadIdx.x == 0) { ls[0] = 0; ls[1] = 0; ls[2] = 0; ls[3] = 0; }
    __syncthreads();
    if ((threadIdx.x & 63) == 0) {
        atomicAdd(&ls[0], s1); atomicAdd(&ls[1], s2);
        atomicAdd(&ls[2], s3); atomicAdd(&ls[3], s4);
    }
    __syncthreads();
    if (threadIdx.x == 0) {
        atomicAdd(&sums[0], ls[0]); atomicAdd(&sums[1], ls[1]);
        atomicAdd(&sums[2], ls[2]); atomicAdd(&sums[3], ls[3]);
    }
}

// -------- Kernel 3: final scalar --------------------------------------------

__global__ void final_kernel(const unsigned int* __restrict__ sums,
                             float* __restrict__ out)
{
    const float eps = 1e-6f;
    const float S1 = (float)sums[0], S2 = (float)sums[1];
    const float S3 = (float)sums[2], S4 = (float)sums[3];
    out[0] = 0.5f * ((S1 + eps) / (S2 + eps) + (S3 + eps) / (S4 + eps));
}

extern "C" void kernel_launch(void* const* d_in, const int* in_sizes, int n_in,
                              void* d_out, int out_size, void* d_ws, size_t ws_size,
                              hipStream_t stream) {
    const float* pred = (const float*)d_in[0];
    const int*   targ = (const int*)d_in[1];
    const size_t npix = (size_t)NIMG * IMG_H * IMG_W;   // 16,777,216

    unsigned char* ws   = (unsigned char*)d_ws;
    unsigned char* gp   = ws;                            // 16 MB
    unsigned char* gt   = ws + npix;                     // 16 MB
    unsigned int*  sums = (unsigned int*)(ws + 2 * npix);
    float* out = (float*)d_out;

    hipMemsetAsync(sums, 0, 4 * sizeof(unsigned int), stream);

    hpass_kernel<<<NIMG * IMG_H, 256, 0, stream>>>(pred, targ, gp, gt);
    vpass_kernel<<<(int)(npix / 1024), 256, 0, stream>>>(gp, gt, sums);
    final_kernel<<<1, 1, 0, stream>>>(sums, out);
}

// Round 2
// 116.823 us; speedup vs baseline: 7.2114x; 7.2114x over previous
//
#include <hip/hip_runtime.h>

#define IMG_H 1024
#define IMG_W 1024
#define NIMG  16
#define MAXD  20
#define VBLOCKS 1024

// -------- Kernel 1: binarize + horizontal (per-row) capped 1-D distance ----
// g(x) = 0 if binary(x)==1 else min(MAXD, distance along the row to the
// nearest binary==1 pixel). Note g==0 <=> binary==1 (encodes the mask too).

__device__ inline int scan1d(const unsigned char* __restrict__ b, int x) {
    if (b[x]) return 0;
    #pragma unroll 1
    for (int d = 1; d <= MAXD; ++d) {
        bool hit = false;
        if (x - d >= 0   && b[x - d]) hit = true;
        if (x + d < IMG_W && b[x + d]) hit = true;
        if (hit) return d;
    }
    return MAXD;
}

__global__ __launch_bounds__(256) void hpass_kernel(
    const float* __restrict__ pred, const int* __restrict__ targ,
    unsigned char* __restrict__ gp, unsigned char* __restrict__ gt)
{
    __shared__ unsigned char pb[IMG_W];
    __shared__ unsigned char tb[IMG_W];
    const int row = blockIdx.x;                      // 0 .. NIMG*IMG_H-1
    const long long base = (long long)row * IMG_W;
    const int tid = threadIdx.x;                     // 256 threads, 4 px each

    const float4 p4 = reinterpret_cast<const float4*>(pred + base)[tid];
    const int4  t4  = reinterpret_cast<const int4*>(targ + base)[tid];
    uchar4 pv, tv;
    pv.x = p4.x > 0.0f; pv.y = p4.y > 0.0f; pv.z = p4.z > 0.0f; pv.w = p4.w > 0.0f;
    tv.x = t4.x != 0;   tv.y = t4.y != 0;   tv.z = t4.z != 0;   tv.w = t4.w != 0;
    reinterpret_cast<uchar4*>(pb)[tid] = pv;
    reinterpret_cast<uchar4*>(tb)[tid] = tv;
    __syncthreads();

    uchar4 gpv, gtv;
    unsigned char* gpp = reinterpret_cast<unsigned char*>(&gpv);
    unsigned char* gtp = reinterpret_cast<unsigned char*>(&gtv);
    #pragma unroll
    for (int j = 0; j < 4; ++j) {
        const int x = tid * 4 + j;
        gpp[j] = (unsigned char)scan1d(pb, x);
        gtp[j] = (unsigned char)scan1d(tb, x);
    }
    reinterpret_cast<uchar4*>(gp + base)[tid] = gpv;
    reinterpret_cast<uchar4*>(gt + base)[tid] = gtv;
}

// -------- Kernel 2: vertical pass D(x,y)=min_d max(d, g(x±d, y)) + reduce ---

__device__ inline void vscan(const unsigned char* __restrict__ g, int base, int r,
                             unsigned int c, int res[4])
{
    int b0 = (int)(c & 255u), b1 = (int)((c >> 8) & 255u);
    int b2 = (int)((c >> 16) & 255u), b3 = (int)((c >> 24) & 255u);
    int bmax = max(max(b0, b1), max(b2, b3));
    #pragma unroll 1
    for (int d = 1; d <= MAXD; ++d) {
        if (bmax <= d) break;                 // all future terms >= d
        unsigned int up = 0xFFFFFFFFu, dn = 0xFFFFFFFFu;
        if (r - d >= 0)    up = *reinterpret_cast<const unsigned int*>(g + base - (d << 10));
        if (r + d < IMG_H) dn = *reinterpret_cast<const unsigned int*>(g + base + (d << 10));
        const int m0 = min((int)(up & 255u),         (int)(dn & 255u));
        const int m1 = min((int)((up >> 8) & 255u),  (int)((dn >> 8) & 255u));
        const int m2 = min((int)((up >> 16) & 255u), (int)((dn >> 16) & 255u));
        const int m3 = min((int)((up >> 24) & 255u), (int)((dn >> 24) & 255u));
        b0 = min(b0, max(d, m0));
        b1 = min(b1, max(d, m1));
        b2 = min(b2, max(d, m2));
        b3 = min(b3, max(d, m3));
        bmax = max(max(b0, b1), max(b2, b3));
    }
    res[0] = b0; res[1] = b1; res[2] = b2; res[3] = b3;
}

__global__ __launch_bounds__(256) void vpass_kernel(
    const unsigned char* __restrict__ gp, const unsigned char* __restrict__ gt,
    uint4* __restrict__ partials)
{
    const int ngroups = NIMG * IMG_H * IMG_W / 4;    // 4,194,304
    const int nthreads = VBLOCKS * 256;              // 262,144
    unsigned int s1 = 0, s2 = 0, s3 = 0, s4 = 0;

    for (int t = blockIdx.x * 256 + threadIdx.x; t < ngroups; t += nthreads) {
        const int base = t * 4;                      // 4 consecutive pixels
        const int r = (t >> 8) & (IMG_H - 1);        // row within image

        const unsigned int cp = *reinterpret_cast<const unsigned int*>(gp + base);
        const unsigned int ct = *reinterpret_cast<const unsigned int*>(gt + base);

        int Dp[4], Dt[4];
        vscan(gp, base, r, cp, Dp);
        vscan(gt, base, r, ct, Dt);

        #pragma unroll
        for (int j = 0; j < 4; ++j) {
            const unsigned int tj = (((ct >> (8 * j)) & 255u) == 0u) ? 1u : 0u; // target==1
            const unsigned int pj = (((cp >> (8 * j)) & 255u) == 0u) ? 1u : 0u; // pred_bin==1
            s1 += tj * (unsigned int)Dp[j];
            s2 += tj;
            s3 += pj * (unsigned int)Dt[j];
            s4 += pj;
        }
    }

    // wave reduce (64 lanes), then LDS combine across 4 waves
    for (int o = 32; o > 0; o >>= 1) {
        s1 += __shfl_down(s1, o);
        s2 += __shfl_down(s2, o);
        s3 += __shfl_down(s3, o);
        s4 += __shfl_down(s4, o);
    }
    __shared__ uint4 wsum[4];
    const int wid = threadIdx.x >> 6;
    if ((threadIdx.x & 63) == 0) wsum[wid] = make_uint4(s1, s2, s3, s4);
    __syncthreads();
    if (threadIdx.x == 0) {
        uint4 a = wsum[0], b = wsum[1], c = wsum[2], d = wsum[3];
        partials[blockIdx.x] = make_uint4(a.x + b.x + c.x + d.x,
                                          a.y + b.y + c.y + d.y,
                                          a.z + b.z + c.z + d.z,
                                          a.w + b.w + c.w + d.w);
    }
}

// -------- Kernel 3: reduce partials + final scalar ---------------------------

__global__ __launch_bounds__(256) void final_kernel(
    const uint4* __restrict__ partials, float* __restrict__ out)
{
    unsigned int s1 = 0, s2 = 0, s3 = 0, s4 = 0;
    for (int i = threadIdx.x; i < VBLOCKS; i += 256) {
        const uint4 p = partials[i];
        s1 += p.x; s2 += p.y; s3 += p.z; s4 += p.w;
    }
    for (int o = 32; o > 0; o >>= 1) {
        s1 += __shfl_down(s1, o);
        s2 += __shfl_down(s2, o);
        s3 += __shfl_down(s3, o);
        s4 += __shfl_down(s4, o);
    }
    __shared__ uint4 wsum[4];
    const int wid = threadIdx.x >> 6;
    if ((threadIdx.x & 63) == 0) wsum[wid] = make_uint4(s1, s2, s3, s4);
    __syncthreads();
    if (threadIdx.x == 0) {
        uint4 a = wsum[0], b = wsum[1], c = wsum[2], d = wsum[3];
        const float eps = 1e-6f;
        const float S1 = (float)(a.x + b.x + c.x + d.x);
        const float S2 = (float)(a.y + b.y + c.y + d.y);
        const float S3 = (float)(a.z + b.z + c.z + d.z);
        const float S4 = (float)(a.w + b.w + c.w + d.w);
        out[0] = 0.5f * ((S1 + eps) / (S2 + eps) + (S3 + eps) / (S4 + eps));
    }
}

extern "C" void kernel_launch(void* const* d_in, const int* in_sizes, int n_in,
                              void* d_out, int out_size, void* d_ws, size_t ws_size,
                              hipStream_t stream) {
    const float* pred = (const float*)d_in[0];
    const int*   targ = (const int*)d_in[1];
    const size_t npix = (size_t)NIMG * IMG_H * IMG_W;   // 16,777,216

    unsigned char* ws   = (unsigned char*)d_ws;
    unsigned char* gp   = ws;                            // 16 MB
    unsigned char* gt   = ws + npix;                     // 16 MB
    uint4*         partials = (uint4*)(ws + 2 * npix);   // 16 KB
    float* out = (float*)d_out;

    hpass_kernel<<<NIMG * IMG_H, 256, 0, stream>>>(pred, targ, gp, gt);
    vpass_kernel<<<VBLOCKS, 256, 0, stream>>>(gp, gt, partials);
    final_kernel<<<1, 256, 0, stream>>>(partials, out);
}

// Round 3
// 94.387 us; speedup vs baseline: 8.9255x; 1.2377x over previous
//
#include <hip/hip_runtime.h>

typedef unsigned long long u64;

#define IMG_H 1024
#define IMG_W 1024
#define NIMG  16
#define WPR   16                      // u64 words per image row (1024 bits)
#define MAXD  20
#define HALO  20
#define TILE_H 32
#define RROWS (TILE_H + 2*HALO)       // 72 rows staged per tile
#define TWORDS (RROWS * WPR)          // 1152 words
#define CWORDS (TILE_H * WPR)         // 512 core words
#define TILES_Y (IMG_H / TILE_H)      // 32
#define NBLK2 (NIMG * TILES_Y)        // 512 blocks for dt_kernel
#define NBLK1 1024                    // blocks for pack_kernel

// -------- Kernel 1: binarize + bit-pack via ballot --------------------------
// bit l of word w corresponds to pixel w*64 + l. Seeds: pred>0 / target!=0.

__global__ __launch_bounds__(256) void pack_kernel(
    const float* __restrict__ pred, const int* __restrict__ targ,
    u64* __restrict__ gp, u64* __restrict__ gt)
{
    const int lane = threadIdx.x & 63;
    const int wave = (blockIdx.x * 256 + threadIdx.x) >> 6;   // 0..4095
    const int nchunks = NIMG * IMG_H * IMG_W / 256;           // 65536

    for (int ci = wave; ci < nchunks; ci += NBLK1 * 4) {
        const int px0 = ci * 256 + lane;
        u64 bp0, bp1, bp2, bp3, bt0, bt1, bt2, bt3;
        bp0 = __ballot(pred[px0        ] > 0.0f);
        bp1 = __ballot(pred[px0 +  64  ] > 0.0f);
        bp2 = __ballot(pred[px0 + 128  ] > 0.0f);
        bp3 = __ballot(pred[px0 + 192  ] > 0.0f);
        bt0 = __ballot(targ[px0        ] != 0);
        bt1 = __ballot(targ[px0 +  64  ] != 0);
        bt2 = __ballot(targ[px0 + 128  ] != 0);
        bt3 = __ballot(targ[px0 + 192  ] != 0);
        if (lane < 4) {
            const u64 wp = lane == 0 ? bp0 : lane == 1 ? bp1 : lane == 2 ? bp2 : bp3;
            const u64 wt = lane == 0 ? bt0 : lane == 1 ? bt1 : lane == 2 ? bt2 : bt3;
            gp[ci * 4 + lane] = wp;
            gt[ci * 4 + lane] = wt;
        }
    }
}

// -------- Kernel 2: iterative bit dilation + fused popcount reduction -------
// D(x) = sum_{k=0..19} [x not covered by dilate^k(seeds)], so
// S_dist = sum_k popcount(other_core & ~dilate^k(seeds)).

__global__ __launch_bounds__(256) void dt_kernel(
    const u64* __restrict__ gp, const u64* __restrict__ gt,
    uint4* __restrict__ partials)
{
    __shared__ u64 S[TWORDS];   // current dilated mask (tile + halo)
    __shared__ u64 D[TWORDS];   // horizontal-dilate temp
    __shared__ u64 C[CWORDS];   // other mask, core rows only

    const int tid = threadIdx.x;
    const int img = blockIdx.x / TILES_Y;
    const int y0  = (blockIdx.x % TILES_Y) * TILE_H;
    const int rowbase = img * IMG_H;

    unsigned int s1 = 0, s2 = 0, s3 = 0, s4 = 0;

    #pragma unroll 1
    for (int stage = 0; stage < 2; ++stage) {
        const u64* dil  = (stage == 0) ? gp : gt;   // mask being dilated
        const u64* core = (stage == 0) ? gt : gp;   // mask being summed over

        for (int idx = tid; idx < TWORDS; idx += 256) {
            const int r = idx >> 4, c = idx & 15;
            const int gy = y0 - HALO + r;
            S[idx] = (gy >= 0 && gy < IMG_H) ? dil[(rowbase + gy) * WPR + c] : 0ULL;
        }
        for (int idx = tid; idx < CWORDS; idx += 256) {
            const int r = idx >> 4, c = idx & 15;
            C[idx] = core[(rowbase + y0 + r) * WPR + c];
        }
        __syncthreads();

        unsigned int sD = 0, sC = 0;
        // k = 0: seeds themselves
        for (int idx = tid; idx < CWORDS; idx += 256) {
            const u64 cw = C[idx];
            sC += __popcll(cw);
            sD += __popcll(cw & ~S[idx + (HALO << 4)]);
        }

        #pragma unroll 1
        for (int k = 1; k < MAXD; ++k) {
            // horizontal dilate S -> D
            for (int idx = tid; idx < TWORDS; idx += 256) {
                const int c = idx & 15;
                const u64 w = S[idx];
                u64 h = w | (w << 1) | (w >> 1);
                if (c > 0)  h |= S[idx - 1] >> 63;
                if (c < 15) h |= S[idx + 1] << 63;
                D[idx] = h;
            }
            __syncthreads();
            // vertical OR D -> S, fused popcount on core rows
            for (int idx = tid; idx < TWORDS; idx += 256) {
                const int r = idx >> 4;
                u64 v = D[idx];
                if (r > 0)         v |= D[idx - WPR];
                if (r < RROWS - 1) v |= D[idx + WPR];
                S[idx] = v;
                if (r >= HALO && r < HALO + TILE_H)
                    sD += __popcll(C[idx - (HALO << 4)] & ~v);
            }
            __syncthreads();
        }

        if (stage == 0) { s1 = sD; s2 = sC; }
        else            { s3 = sD; s4 = sC; }
        __syncthreads();   // protect S/C before next stage reload
    }

    // wave reduce, then LDS combine across 4 waves
    for (int o = 32; o > 0; o >>= 1) {
        s1 += __shfl_down(s1, o);
        s2 += __shfl_down(s2, o);
        s3 += __shfl_down(s3, o);
        s4 += __shfl_down(s4, o);
    }
    __shared__ uint4 wsum[4];
    const int wid = tid >> 6;
    if ((tid & 63) == 0) wsum[wid] = make_uint4(s1, s2, s3, s4);
    __syncthreads();
    if (tid == 0) {
        uint4 a = wsum[0], b = wsum[1], c = wsum[2], d = wsum[3];
        partials[blockIdx.x] = make_uint4(a.x + b.x + c.x + d.x,
                                          a.y + b.y + c.y + d.y,
                                          a.z + b.z + c.z + d.z,
                                          a.w + b.w + c.w + d.w);
    }
}

// -------- Kernel 3: reduce partials + final scalar ---------------------------

__global__ __launch_bounds__(256) void final_kernel(
    const uint4* __restrict__ partials, float* __restrict__ out)
{
    unsigned int s1 = 0, s2 = 0, s3 = 0, s4 = 0;
    for (int i = threadIdx.x; i < NBLK2; i += 256) {
        const uint4 p = partials[i];
        s1 += p.x; s2 += p.y; s3 += p.z; s4 += p.w;
    }
    for (int o = 32; o > 0; o >>= 1) {
        s1 += __shfl_down(s1, o);
        s2 += __shfl_down(s2, o);
        s3 += __shfl_down(s3, o);
        s4 += __shfl_down(s4, o);
    }
    __shared__ uint4 wsum[4];
    const int wid = threadIdx.x >> 6;
    if ((threadIdx.x & 63) == 0) wsum[wid] = make_uint4(s1, s2, s3, s4);
    __syncthreads();
    if (threadIdx.x == 0) {
        uint4 a = wsum[0], b = wsum[1], c = wsum[2], d = wsum[3];
        const float eps = 1e-6f;
        const float S1 = (float)(a.x + b.x + c.x + d.x);
        const float S2 = (float)(a.y + b.y + c.y + d.y);
        const float S3 = (float)(a.z + b.z + c.z + d.z);
        const float S4 = (float)(a.w + b.w + c.w + d.w);
        out[0] = 0.5f * ((S1 + eps) / (S2 + eps) + (S3 + eps) / (S4 + eps));
    }
}

extern "C" void kernel_launch(void* const* d_in, const int* in_sizes, int n_in,
                              void* d_out, int out_size, void* d_ws, size_t ws_size,
                              hipStream_t stream) {
    const float* pred = (const float*)d_in[0];
    const int*   targ = (const int*)d_in[1];
    const size_t nwords = (size_t)NIMG * IMG_H * IMG_W / 64;   // 262,144

    u64*   gp       = (u64*)d_ws;                              // 2 MB
    u64*   gt       = gp + nwords;                             // 2 MB
    uint4* partials = (uint4*)(gt + nwords);                   // 8 KB
    float* out = (float*)d_out;

    pack_kernel<<<NBLK1, 256, 0, stream>>>(pred, targ, gp, gt);
    dt_kernel<<<NBLK2, 256, 0, stream>>>(gp, gt, partials);
    final_kernel<<<1, 256, 0, stream>>>(partials, out);
}

// Round 4
// 42.110 us; speedup vs baseline: 20.0061x; 2.2415x over previous
//
#include <hip/hip_runtime.h>

typedef unsigned long long u64;

#define IMG_H 1024
#define IMG_W 1024
#define NIMG  16
#define WPR   16                      // u64 words per image row (1024 bits)
#define MAXD  20
#define HALO  19                      // cov_k (k<=19) reach
#define CORE  26                      // 64 = HALO + CORE + HALO
#define TILES_Y 40                    // ceil(1024/26); cores partition [0,1040)
#define NBLK2 (NIMG * TILES_Y * 2)    // 1280 single-wave blocks
#define NBLK1 1024                    // blocks for pack_kernel

// -------- Kernel 1: binarize + bit-pack via ballot --------------------------
// bit l of word w corresponds to pixel w*64 + l. Seeds: pred>0 / target!=0.

__global__ __launch_bounds__(256) void pack_kernel(
    const float* __restrict__ pred, const int* __restrict__ targ,
    u64* __restrict__ gp, u64* __restrict__ gt)
{
    const int lane = threadIdx.x & 63;
    const int wave = (blockIdx.x * 256 + threadIdx.x) >> 6;   // 0..4095
    const int nchunks = NIMG * IMG_H * IMG_W / 256;           // 65536

    for (int ci = wave; ci < nchunks; ci += NBLK1 * 4) {
        const int px0 = ci * 256 + lane;
        u64 bp0, bp1, bp2, bp3, bt0, bt1, bt2, bt3;
        bp0 = __ballot(pred[px0        ] > 0.0f);
        bp1 = __ballot(pred[px0 +  64  ] > 0.0f);
        bp2 = __ballot(pred[px0 + 128  ] > 0.0f);
        bp3 = __ballot(pred[px0 + 192  ] > 0.0f);
        bt0 = __ballot(targ[px0        ] != 0);
        bt1 = __ballot(targ[px0 +  64  ] != 0);
        bt2 = __ballot(targ[px0 + 128  ] != 0);
        bt3 = __ballot(targ[px0 + 192  ] != 0);
        if (lane < 4) {
            const u64 wp = lane == 0 ? bp0 : lane == 1 ? bp1 : lane == 2 ? bp2 : bp3;
            const u64 wt = lane == 0 ? bt0 : lane == 1 ? bt1 : lane == 2 ? bt2 : bt3;
            gp[ci * 4 + lane] = wp;
            gt[ci * 4 + lane] = wt;
        }
    }
}

// -------- Kernel 2: register-resident bit dilation, one row per lane --------
// S_dist = sum_{k=0..19} popcount(C & ~dilate^k(seeds)).
// Single-wave blocks: vertical exchange via shfl, zero barriers.

__device__ inline u64 shfl_up1_u64(u64 x) {
    unsigned int lo = (unsigned int)x, hi = (unsigned int)(x >> 32);
    lo = __shfl_up(lo, 1);
    hi = __shfl_up(hi, 1);
    return ((u64)hi << 32) | (u64)lo;
}
__device__ inline u64 shfl_dn1_u64(u64 x) {
    unsigned int lo = (unsigned int)x, hi = (unsigned int)(x >> 32);
    lo = __shfl_down(lo, 1);
    hi = __shfl_down(hi, 1);
    return ((u64)hi << 32) | (u64)lo;
}

__global__ __launch_bounds__(64) void dt_kernel(
    const u64* __restrict__ gp, const u64* __restrict__ gt,
    uint4* __restrict__ partials)
{
    const int l     = threadIdx.x;
    const int stage = blockIdx.x & 1;
    const int tile  = (blockIdx.x >> 1) % TILES_Y;
    const int img   = blockIdx.x / (2 * TILES_Y);
    const int y0    = tile * CORE;                 // core rows [y0, y0+CORE)
    const int gy    = y0 - HALO + l;               // this lane's row
    const bool inimg = (gy >= 0 && gy < IMG_H);
    const u64 alive  = inimg ? ~0ULL : 0ULL;
    const bool core  = (l >= HALO) && (l < HALO + CORE) && (gy < IMG_H);

    const u64* __restrict__ dil = (stage == 0) ? gp : gt;  // dilated mask
    const u64* __restrict__ oth = (stage == 0) ? gt : gp;  // summed-over mask
    const long long rb = ((long long)img * IMG_H + gy) * WPR;

    u64 s[16], C[16];
    #pragma unroll
    for (int c = 0; c < 16; ++c) {
        s[c] = inimg ? dil[rb + c] : 0ULL;
        C[c] = core  ? oth[rb + c] : 0ULL;   // C==0 off-core => popcounts self-mask
    }

    unsigned int sD = 0, sC = 0;
    #pragma unroll
    for (int c = 0; c < 16; ++c) {           // k = 0 term
        sC += (unsigned int)__popcll(C[c]);
        sD += (unsigned int)__popcll(C[c] & ~s[c]);
    }

    #pragma unroll 1
    for (int k = 1; k < MAXD; ++k) {
        // saturation early-exit: monotone OR; once all in-image rows are
        // all-ones, every remaining round contributes exactly 0.
        u64 andall = ~0ULL;
        #pragma unroll
        for (int c = 0; c < 16; ++c) andall &= s[c];
        if (__all(!inimg || (andall == ~0ULL))) break;

        u64 h[16];
        #pragma unroll
        for (int c = 0; c < 16; ++c)          // in-word horizontal dilate
            h[c] = s[c] | (s[c] << 1) | (s[c] >> 1);
        #pragma unroll
        for (int c = 0; c < 15; ++c) {        // cross-word carries
            h[c]     |= s[c + 1] << 63;
            h[c + 1] |= s[c] >> 63;
        }
        #pragma unroll
        for (int c = 0; c < 16; ++c) {        // vertical OR via shfl, fused popcount
            const u64 up = shfl_up1_u64(h[c]);
            const u64 dn = shfl_dn1_u64(h[c]);
            const u64 v  = (h[c] | up | dn) & alive;
            s[c] = v;
            sD += (unsigned int)__popcll(C[c] & ~v);
        }
    }
    // rounds that broke early contribute 0 by saturation; if loop ran all 19
    // rounds, remaining uncovered core pixels already accumulated 20 terms.

    // 64-lane reduce of (sD, sC)
    for (int o = 32; o > 0; o >>= 1) {
        sD += __shfl_down(sD, o);
        sC += __shfl_down(sC, o);
    }
    if (l == 0) {
        partials[blockIdx.x] = (stage == 0) ? make_uint4(sD, sC, 0u, 0u)
                                            : make_uint4(0u, 0u, sD, sC);
    }
}

// -------- Kernel 3: reduce partials + final scalar ---------------------------

__global__ __launch_bounds__(256) void final_kernel(
    const uint4* __restrict__ partials, float* __restrict__ out)
{
    unsigned int s1 = 0, s2 = 0, s3 = 0, s4 = 0;
    for (int i = threadIdx.x; i < NBLK2; i += 256) {
        const uint4 p = partials[i];
        s1 += p.x; s2 += p.y; s3 += p.z; s4 += p.w;
    }
    for (int o = 32; o > 0; o >>= 1) {
        s1 += __shfl_down(s1, o);
        s2 += __shfl_down(s2, o);
        s3 += __shfl_down(s3, o);
        s4 += __shfl_down(s4, o);
    }
    __shared__ uint4 wsum[4];
    const int wid = threadIdx.x >> 6;
    if ((threadIdx.x & 63) == 0) wsum[wid] = make_uint4(s1, s2, s3, s4);
    __syncthreads();
    if (threadIdx.x == 0) {
        uint4 a = wsum[0], b = wsum[1], c = wsum[2], d = wsum[3];
        const float eps = 1e-6f;
        const float S1 = (float)(a.x + b.x + c.x + d.x);
        const float S2 = (float)(a.y + b.y + c.y + d.y);
        const float S3 = (float)(a.z + b.z + c.z + d.z);
        const float S4 = (float)(a.w + b.w + c.w + d.w);
        out[0] = 0.5f * ((S1 + eps) / (S2 + eps) + (S3 + eps) / (S4 + eps));
    }
}

extern "C" void kernel_launch(void* const* d_in, const int* in_sizes, int n_in,
                              void* d_out, int out_size, void* d_ws, size_t ws_size,
                              hipStream_t stream) {
    const float* pred = (const float*)d_in[0];
    const int*   targ = (const int*)d_in[1];
    const size_t nwords = (size_t)NIMG * IMG_H * IMG_W / 64;   // 262,144

    u64*   gp       = (u64*)d_ws;                              // 2 MB
    u64*   gt       = gp + nwords;                             // 2 MB
    uint4* partials = (uint4*)(gt + nwords);                   // 20 KB
    float* out = (float*)d_out;

    pack_kernel<<<NBLK1, 256, 0, stream>>>(pred, targ, gp, gt);
    dt_kernel<<<NBLK2, 64, 0, stream>>>(gp, gt, partials);
    final_kernel<<<1, 256, 0, stream>>>(partials, out);
}

// Round 5
// 41.627 us; speedup vs baseline: 20.2384x; 1.0116x over previous
//
#include <hip/hip_runtime.h>

typedef unsigned long long u64;

#define IMG_H 1024
#define IMG_W 1024
#define NIMG  16
#define WPR   16                      // u64 words per image row (1024 bits)
#define MAXD  20
#define HALO  19                      // cov_k (k<=19) reach
#define CORE  26                      // 64 = HALO + CORE + HALO
#define TILES_Y 40                    // ceil(1024/26); cores partition [0,1040)
#define NBLK2 (NIMG * TILES_Y * 2)    // 1280 single-wave blocks
#define PBLK  2048                    // blocks for pack_kernel

// -------- Kernel 1: binarize + bit-pack, 16 px/lane, LDS u16 assembly -------
// bit b of word w corresponds to pixel w*64 + b. Seeds: pred>0 / target!=0.

__global__ __launch_bounds__(256) void pack_kernel(
    const float* __restrict__ pred, const int* __restrict__ targ,
    u64* __restrict__ gp, u64* __restrict__ gt)
{
    __shared__ unsigned short mp[256];
    __shared__ unsigned short mt[256];
    const int tid = threadIdx.x;
    const int nchunks = NIMG * IMG_H * IMG_W / 4096;   // 4096 chunks

    for (int ci = blockIdx.x; ci < nchunks; ci += PBLK) {
        const long long px = (long long)ci * 4096 + tid * 16;
        const float4* __restrict__ p4 = reinterpret_cast<const float4*>(pred + px);
        const int4*  __restrict__ t4 = reinterpret_cast<const int4*>(targ + px);

        unsigned int m_p = 0, m_t = 0;
        #pragma unroll
        for (int n = 0; n < 4; ++n) {
            const float4 p = p4[n];
            const int4  t = t4[n];
            m_p |= ((unsigned int)(p.x > 0.0f) << (4*n))
                 | ((unsigned int)(p.y > 0.0f) << (4*n+1))
                 | ((unsigned int)(p.z > 0.0f) << (4*n+2))
                 | ((unsigned int)(p.w > 0.0f) << (4*n+3));
            m_t |= ((unsigned int)(t.x != 0) << (4*n))
                 | ((unsigned int)(t.y != 0) << (4*n+1))
                 | ((unsigned int)(t.z != 0) << (4*n+2))
                 | ((unsigned int)(t.w != 0) << (4*n+3));
        }
        mp[tid] = (unsigned short)m_p;
        mt[tid] = (unsigned short)m_t;
        __syncthreads();

        if (tid < 64) {
            // 4 adjacent u16 lane-masks ARE the output u64 (little-endian)
            const u64 wp = reinterpret_cast<const u64*>(mp)[tid];
            const u64 wt = reinterpret_cast<const u64*>(mt)[tid];
            gp[(long long)ci * 64 + tid] = wp;
            gt[(long long)ci * 64 + tid] = wt;
        }
        __syncthreads();   // protect mp/mt before next iteration overwrites
    }
}

// -------- Kernel 2: register-resident bit dilation, one row per lane --------
// S_dist = sum_{k=0..19} popcount(C & ~dilate^k(seeds)).
// Single-wave blocks: vertical exchange via shfl, zero barriers.

__device__ inline u64 shfl_up1_u64(u64 x) {
    unsigned int lo = (unsigned int)x, hi = (unsigned int)(x >> 32);
    lo = __shfl_up(lo, 1);
    hi = __shfl_up(hi, 1);
    return ((u64)hi << 32) | (u64)lo;
}
__device__ inline u64 shfl_dn1_u64(u64 x) {
    unsigned int lo = (unsigned int)x, hi = (unsigned int)(x >> 32);
    lo = __shfl_down(lo, 1);
    hi = __shfl_down(hi, 1);
    return ((u64)hi << 32) | (u64)lo;
}

__global__ __launch_bounds__(64) void dt_kernel(
    const u64* __restrict__ gp, const u64* __restrict__ gt,
    uint4* __restrict__ partials)
{
    const int l     = threadIdx.x;
    const int stage = blockIdx.x & 1;
    const int tile  = (blockIdx.x >> 1) % TILES_Y;
    const int img   = blockIdx.x / (2 * TILES_Y);
    const int y0    = tile * CORE;                 // core rows [y0, y0+CORE)
    const int gy    = y0 - HALO + l;               // this lane's row
    const bool inimg = (gy >= 0 && gy < IMG_H);
    const u64 alive  = inimg ? ~0ULL : 0ULL;
    const bool core  = (l >= HALO) && (l < HALO + CORE) && (gy < IMG_H);

    const u64* __restrict__ dil = (stage == 0) ? gp : gt;  // dilated mask
    const u64* __restrict__ oth = (stage == 0) ? gt : gp;  // summed-over mask
    const long long rb = ((long long)img * IMG_H + gy) * WPR;

    u64 s[16], C[16];
    #pragma unroll
    for (int c = 0; c < 16; ++c) {
        s[c] = inimg ? dil[rb + c] : 0ULL;
        C[c] = core  ? oth[rb + c] : 0ULL;   // C==0 off-core => popcounts self-mask
    }

    unsigned int sD = 0, sC = 0;
    #pragma unroll
    for (int c = 0; c < 16; ++c) {           // k = 0 term
        sC += (unsigned int)__popcll(C[c]);
        sD += (unsigned int)__popcll(C[c] & ~s[c]);
    }

    #pragma unroll 1
    for (int k = 1; k < MAXD; ++k) {
        // saturation early-exit: monotone OR; once all in-image rows are
        // all-ones, every remaining round contributes exactly 0.
        u64 andall = ~0ULL;
        #pragma unroll
        for (int c = 0; c < 16; ++c) andall &= s[c];
        if (__all(!inimg || (andall == ~0ULL))) break;

        u64 h[16];
        #pragma unroll
        for (int c = 0; c < 16; ++c)          // in-word horizontal dilate
            h[c] = s[c] | (s[c] << 1) | (s[c] >> 1);
        #pragma unroll
        for (int c = 0; c < 15; ++c) {        // cross-word carries
            h[c]     |= s[c + 1] << 63;
            h[c + 1] |= s[c] >> 63;
        }
        #pragma unroll
        for (int c = 0; c < 16; ++c) {        // vertical OR via shfl, fused popcount
            const u64 up = shfl_up1_u64(h[c]);
            const u64 dn = shfl_dn1_u64(h[c]);
            const u64 v  = (h[c] | up | dn) & alive;
            s[c] = v;
            sD += (unsigned int)__popcll(C[c] & ~v);
        }
    }
    // rounds that broke early contribute 0 by saturation; if loop ran all 19
    // rounds, remaining uncovered core pixels already accumulated 20 terms.

    // 64-lane reduce of (sD, sC)
    for (int o = 32; o > 0; o >>= 1) {
        sD += __shfl_down(sD, o);
        sC += __shfl_down(sC, o);
    }
    if (l == 0) {
        partials[blockIdx.x] = (stage == 0) ? make_uint4(sD, sC, 0u, 0u)
                                            : make_uint4(0u, 0u, sD, sC);
    }
}

// -------- Kernel 3: reduce partials + final scalar ---------------------------

__global__ __launch_bounds__(256) void final_kernel(
    const uint4* __restrict__ partials, float* __restrict__ out)
{
    unsigned int s1 = 0, s2 = 0, s3 = 0, s4 = 0;
    for (int i = threadIdx.x; i < NBLK2; i += 256) {
        const uint4 p = partials[i];
        s1 += p.x; s2 += p.y; s3 += p.z; s4 += p.w;
    }
    for (int o = 32; o > 0; o >>= 1) {
        s1 += __shfl_down(s1, o);
        s2 += __shfl_down(s2, o);
        s3 += __shfl_down(s3, o);
        s4 += __shfl_down(s4, o);
    }
    __shared__ uint4 wsum[4];
    const int wid = threadIdx.x >> 6;
    if ((threadIdx.x & 63) == 0) wsum[wid] = make_uint4(s1, s2, s3, s4);
    __syncthreads();
    if (threadIdx.x == 0) {
        uint4 a = wsum[0], b = wsum[1], c = wsum[2], d = wsum[3];
        const float eps = 1e-6f;
        const float S1 = (float)(a.x + b.x + c.x + d.x);
        const float S2 = (float)(a.y + b.y + c.y + d.y);
        const float S3 = (float)(a.z + b.z + c.z + d.z);
        const float S4 = (float)(a.w + b.w + c.w + d.w);
        out[0] = 0.5f * ((S1 + eps) / (S2 + eps) + (S3 + eps) / (S4 + eps));
    }
}

extern "C" void kernel_launch(void* const* d_in, const int* in_sizes, int n_in,
                              void* d_out, int out_size, void* d_ws, size_t ws_size,
                              hipStream_t stream) {
    const float* pred = (const float*)d_in[0];
    const int*   targ = (const int*)d_in[1];
    const size_t nwords = (size_t)NIMG * IMG_H * IMG_W / 64;   // 262,144

    u64*   gp       = (u64*)d_ws;                              // 2 MB
    u64*   gt       = gp + nwords;                             // 2 MB
    uint4* partials = (uint4*)(gt + nwords);                   // 20 KB
    float* out = (float*)d_out;

    pack_kernel<<<PBLK, 256, 0, stream>>>(pred, targ, gp, gt);
    dt_kernel<<<NBLK2, 64, 0, stream>>>(gp, gt, partials);
    final_kernel<<<1, 256, 0, stream>>>(partials, out);
}